// Round 3
// baseline (176.816 us; speedup 1.0000x reference)
//
#include <hip/hip_runtime.h>

#define NROWS 2048
#define KDIM  128
#define TJ    64

__device__ __forceinline__ float fexp2(float x){ return __builtin_amdgcn_exp2f(x); }
__device__ __forceinline__ float flog2(float x){ return __builtin_amdgcn_logf(x); }

// sqrt(1/(2*ln2)): (t*CS)^2 = t^2/(2 ln 2), so exp2(-(t*CS)^2) = exp(-t^2/2)
#define CS 0.8493218002880191f

// ---------------- Kernel A: per-column mean / unbiased std -> scale, shift ----
__global__ __launch_bounds__(256) void tc_stats(const float* __restrict__ x,
                                                float* __restrict__ stats){
  const int k = blockIdx.x;          // 0..127
  const int t = threadIdx.x;
  float s = 0.f, s2 = 0.f;
  for (int r = t; r < NROWS; r += 256){
    float v = x[(size_t)r * KDIM + k];
    s += v;
    s2 = fmaf(v, v, s2);
  }
  for (int off = 32; off > 0; off >>= 1){
    s  += __shfl_down(s,  off);
    s2 += __shfl_down(s2, off);
  }
  __shared__ float rs[4], rs2[4];
  const int wave = t >> 6, lane = t & 63;
  if (lane == 0){ rs[wave] = s; rs2[wave] = s2; }
  __syncthreads();
  if (t == 0){
    s  = rs[0] + rs[1] + rs[2] + rs[3];
    s2 = rs2[0] + rs2[1] + rs2[2] + rs2[3];
    float mean = s * (1.f / NROWS);
    float var  = fmaxf((s2 - (float)NROWS * mean * mean) * (1.f / (NROWS - 1)), 0.f);
    float scale = 1.f / (sqrtf(var) + 1e-6f);
    stats[k]        = scale;         // x_std = x*scale + shift
    stats[KDIM + k] = -mean * scale;
  }
}

// ---------------- Kernel B: main pairwise pass -------------------------------
// Wave: 4 rows (g = lane>>4), 16 lanes per row (h = lane&15), k-slices {4h..4h+3, 64+4h..64+4h+3}
// Block: 512 threads = 8 waves = 32 rows. Grid: (64 i-tiles, 8 j-chunks of 256).
__global__ __launch_bounds__(512) void tc_main(const float* __restrict__ x,
                                               const float* __restrict__ stats,
                                               float* __restrict__ marg,
                                               float* __restrict__ joint){
  __shared__ float tile[TJ][KDIM];   // 32 KB
  const int t    = threadIdx.x;
  const int wave = t >> 6;
  const int lane = t & 63;
  const int g    = lane >> 4;
  const int h    = lane & 15;
  const int row  = blockIdx.x * 32 + wave * 4 + g;
  const int jbase = blockIdx.y * 256;

  // staging constants: thread t always stages quad column kq = t&31
  const int kq = t & 31;
  const float4 sc4 = reinterpret_cast<const float4*>(stats)[kq];
  const float4 sh4 = reinterpret_cast<const float4*>(stats + KDIM)[kq];

  // xi (standardized) for this lane's 8 k's
  float4 xiA = reinterpret_cast<const float4*>(x + (size_t)row * KDIM)[h];
  float4 xiB = reinterpret_cast<const float4*>(x + (size_t)row * KDIM)[16 + h];
  {
    const float4 sA = reinterpret_cast<const float4*>(stats)[h];
    const float4 hA = reinterpret_cast<const float4*>(stats + KDIM)[h];
    const float4 sB = reinterpret_cast<const float4*>(stats)[16 + h];
    const float4 hB = reinterpret_cast<const float4*>(stats + KDIM)[16 + h];
    xiA.x = fmaf(xiA.x, sA.x, hA.x); xiA.y = fmaf(xiA.y, sA.y, hA.y);
    xiA.z = fmaf(xiA.z, sA.z, hA.z); xiA.w = fmaf(xiA.w, sA.w, hA.w);
    xiB.x = fmaf(xiB.x, sB.x, hB.x); xiB.y = fmaf(xiB.y, sB.y, hB.y);
    xiB.z = fmaf(xiB.z, sB.z, hB.z); xiB.w = fmaf(xiB.w, sB.w, hB.w);
  }

  float S0=0.f,S1=0.f,S2=0.f,S3=0.f,S4=0.f,S5=0.f,S6=0.f,S7=0.f;
  float jacc = 0.f;
  const int jr0 = t >> 5;

  for (int jt = 0; jt < 256; jt += TJ){
    __syncthreads();
    #pragma unroll
    for (int p = 0; p < 4; ++p){
      const int jr = jr0 + 16 * p;
      float4 v = reinterpret_cast<const float4*>(x + (size_t)(jbase + jt + jr) * KDIM)[kq];
      float4 w;
      w.x = fmaf(v.x, sc4.x, sh4.x);
      w.y = fmaf(v.y, sc4.y, sh4.y);
      w.z = fmaf(v.z, sc4.z, sh4.z);
      w.w = fmaf(v.w, sc4.w, sh4.w);
      *reinterpret_cast<float4*>(&tile[jr][kq * 4]) = w;
    }
    __syncthreads();

    for (int j = 0; j < TJ; ++j){
      const float4 a = *reinterpret_cast<const float4*>(&tile[j][4 * h]);
      const float4 b = *reinterpret_cast<const float4*>(&tile[j][64 + 4 * h]);
      float pd = 0.f;
      float tt, u, d;
      tt = xiA.x - a.x; u = tt * CS; d = u * u; pd += d; S0 += fexp2(-d);
      tt = xiA.y - a.y; u = tt * CS; d = u * u; pd += d; S1 += fexp2(-d);
      tt = xiA.z - a.z; u = tt * CS; d = u * u; pd += d; S2 += fexp2(-d);
      tt = xiA.w - a.w; u = tt * CS; d = u * u; pd += d; S3 += fexp2(-d);
      tt = xiB.x - b.x; u = tt * CS; d = u * u; pd += d; S4 += fexp2(-d);
      tt = xiB.y - b.y; u = tt * CS; d = u * u; pd += d; S5 += fexp2(-d);
      tt = xiB.z - b.z; u = tt * CS; d = u * u; pd += d; S6 += fexp2(-d);
      tt = xiB.w - b.w; u = tt * CS; d = u * u; pd += d; S7 += fexp2(-d);
      // joint: reduce scaled sqdist over the 16 lanes of this row-group
      pd += __shfl_xor(pd, 1);
      pd += __shfl_xor(pd, 2);
      pd += __shfl_xor(pd, 4);
      pd += __shfl_xor(pd, 8);
      jacc += fexp2(-pd);
    }
  }

  float* mrow = marg + (size_t)row * KDIM;
  atomicAdd(&mrow[4 * h + 0], S0);
  atomicAdd(&mrow[4 * h + 1], S1);
  atomicAdd(&mrow[4 * h + 2], S2);
  atomicAdd(&mrow[4 * h + 3], S3);
  atomicAdd(&mrow[64 + 4 * h + 0], S4);
  atomicAdd(&mrow[64 + 4 * h + 1], S5);
  atomicAdd(&mrow[64 + 4 * h + 2], S6);
  atomicAdd(&mrow[64 + 4 * h + 3], S7);
  if (h == 0) atomicAdd(&joint[row], jacc);
}

// ---------------- Kernel C: finalize ----------------------------------------
// v_i = ln2*(log2 Sj - sum_k log2 Sk) + 127*ln(2048); out = mean_i v_i
__global__ __launch_bounds__(256) void tc_final(const float* __restrict__ marg,
                                                const float* __restrict__ joint,
                                                float* __restrict__ out){
  const int r = blockIdx.x * 256 + threadIdx.x;
  const float* m = marg + (size_t)r * KDIM;
  float s = 0.f;
  #pragma unroll 4
  for (int k4 = 0; k4 < KDIM / 4; ++k4){
    float4 v = reinterpret_cast<const float4*>(m)[k4];
    s += flog2(v.x) + flog2(v.y) + flog2(v.z) + flog2(v.w);
  }
  // 127 * ln(2048) = 127 * 11 * ln 2
  float vi = 0.6931471805599453f * (flog2(joint[r]) - s) + 968.32661124224364f;
  for (int off = 32; off > 0; off >>= 1) vi += __shfl_down(vi, off);
  __shared__ float rs[4];
  const int wave = threadIdx.x >> 6, lane = threadIdx.x & 63;
  if (lane == 0) rs[wave] = vi;
  __syncthreads();
  if (threadIdx.x == 0){
    float tot = rs[0] + rs[1] + rs[2] + rs[3];
    atomicAdd(out, tot * (1.0f / NROWS));
  }
}

// ---------------- launch -----------------------------------------------------
extern "C" void kernel_launch(void* const* d_in, const int* in_sizes, int n_in,
                              void* d_out, int out_size, void* d_ws, size_t ws_size,
                              hipStream_t stream){
  const float* x = (const float*)d_in[0];
  float* out   = (float*)d_out;
  float* wsf   = (float*)d_ws;
  float* stats = wsf;                         // 256 floats
  float* joint = wsf + 2 * KDIM;              // 2048 floats
  float* marg  = wsf + 2 * KDIM + NROWS;      // 2048*128 floats
  // zero the accumulators (ws is poisoned before every timed launch)
  (void)hipMemsetAsync(joint, 0, (size_t)(NROWS + NROWS * KDIM) * sizeof(float), stream);
  (void)hipMemsetAsync(d_out, 0, sizeof(float), stream);

  tc_stats<<<KDIM, 256, 0, stream>>>(x, stats);
  tc_main<<<dim3(64, 8), 512, 0, stream>>>(x, stats, marg, joint);
  tc_final<<<NROWS / 256, 256, 0, stream>>>(marg, joint, out);
}

// Round 4
// 163.538 us; speedup vs baseline: 1.0812x; 1.0812x over previous
//
#include <hip/hip_runtime.h>

#define NROWS 2048
#define KDIM  128
#define TJ    64

typedef float v4f __attribute__((ext_vector_type(4)));

__device__ __forceinline__ float fexp2(float x){ return __builtin_amdgcn_exp2f(x); }
__device__ __forceinline__ float flog2(float x){ return __builtin_amdgcn_logf(x); }

// sqrt(1/(2*ln2)): with x' = CS*x_std, exp2(-(x'_i-x'_j)^2) = exp(-(xstd_i-xstd_j)^2/2)
#define CS 0.8493218002880191f

// DPP row-rotate-right by N within 16-lane rows, returned as float
template<int CTRL>
__device__ __forceinline__ float dpp_ror(float v){
  int r = __builtin_amdgcn_update_dpp(0, __builtin_bit_cast(int, v), CTRL, 0xF, 0xF, true);
  return __builtin_bit_cast(float, r);
}

// ---------------- Kernel A: raw column sums (coalesced) ----------------------
// 32 blocks x 1024 threads; block handles 64 contiguous rows. accum[k]=sum, accum[128+k]=sumsq
__global__ __launch_bounds__(1024) void tc_stats(const float* __restrict__ x,
                                                 float* __restrict__ accum){
  const int t  = threadIdx.x;
  const int k  = t & 127;
  const int rg = t >> 7;               // 0..7
  const int r0 = blockIdx.x * 64;
  float s = 0.f, s2 = 0.f;
  #pragma unroll
  for (int it = 0; it < 8; ++it){
    float v = x[(size_t)(r0 + it * 8 + rg) * KDIM + k];
    s += v;
    s2 = fmaf(v, v, s2);
  }
  __shared__ float ls[8][128], ls2[8][128];
  ls[rg][k] = s; ls2[rg][k] = s2;
  __syncthreads();
  if (t < 128){
    float a = 0.f, b = 0.f;
    #pragma unroll
    for (int g = 0; g < 8; ++g){ a += ls[g][t]; b += ls2[g][t]; }
    atomicAdd(&accum[t], a);
    atomicAdd(&accum[128 + t], b);
  }
}

// derive CS-folded scale/shift for k-quad q from raw sums
__device__ __forceinline__ void quad_stats(const float* __restrict__ accum, int q,
                                           float4& sc, float4& sh){
  const float4 s  = reinterpret_cast<const float4*>(accum)[q];
  const float4 s2 = reinterpret_cast<const float4*>(accum + KDIM)[q];
  const float invN = 1.f / NROWS, invN1 = 1.f / (NROWS - 1);
#define COMP(c) { float m = s.c * invN; \
                  float var = fmaxf((s2.c - (float)NROWS * m * m) * invN1, 0.f); \
                  float sca = CS / (sqrtf(var) + 1e-6f); sc.c = sca; sh.c = -m * sca; }
  COMP(x) COMP(y) COMP(z) COMP(w)
#undef COMP
}

// ---------------- Kernel B: main pairwise pass -------------------------------
// Wave: 4 rows (g=lane>>4), 16 lanes/row (h=lane&15), k-slices {4h..4h+3, 64+4h..64+4h+3}
// Block: 512 threads = 8 waves = 32 rows. Grid: (64 i-tiles, 8 j-chunks of 256).
__global__ __launch_bounds__(512) void tc_main(const float* __restrict__ x,
                                               const float* __restrict__ accum,
                                               float* __restrict__ marg,
                                               float* __restrict__ joint){
  __shared__ float tile[TJ][KDIM];     // 32 KB
  const int t    = threadIdx.x;
  const int wave = t >> 6;
  const int lane = t & 63;
  const int g    = lane >> 4;
  const int h    = lane & 15;
  const int row  = blockIdx.x * 32 + wave * 4 + g;
  const int jbase = blockIdx.y * 256;

  const int kq = t & 31;               // staging quad column
  float4 sc4, sh4; quad_stats(accum, kq, sc4, sh4);

  // xi (standardized*CS) for this lane's 8 k's
  v4f xA, xB;
  {
    float4 scA, shA, scB, shB;
    quad_stats(accum, h,      scA, shA);
    quad_stats(accum, 16 + h, scB, shB);
    float4 rA = reinterpret_cast<const float4*>(x + (size_t)row * KDIM)[h];
    float4 rB = reinterpret_cast<const float4*>(x + (size_t)row * KDIM)[16 + h];
    xA = (v4f){fmaf(rA.x, scA.x, shA.x), fmaf(rA.y, scA.y, shA.y),
               fmaf(rA.z, scA.z, shA.z), fmaf(rA.w, scA.w, shA.w)};
    xB = (v4f){fmaf(rB.x, scB.x, shB.x), fmaf(rB.y, scB.y, shB.y),
               fmaf(rB.z, scB.z, shB.z), fmaf(rB.w, scB.w, shB.w)};
  }

  v4f SA = {0.f,0.f,0.f,0.f}, SB = {0.f,0.f,0.f,0.f};
  float jacc = 0.f;
  const int jr0 = t >> 5;

  for (int jt = 0; jt < 256; jt += TJ){
    __syncthreads();
    #pragma unroll
    for (int p = 0; p < 4; ++p){
      const int jr = jr0 + 16 * p;
      float4 v = reinterpret_cast<const float4*>(x + (size_t)(jbase + jt + jr) * KDIM)[kq];
      v4f w = {fmaf(v.x, sc4.x, sh4.x), fmaf(v.y, sc4.y, sh4.y),
               fmaf(v.z, sc4.z, sh4.z), fmaf(v.w, sc4.w, sh4.w)};
      *reinterpret_cast<v4f*>(&tile[jr][kq * 4]) = w;
    }
    __syncthreads();

    for (int j = 0; j < TJ; ++j){
      const v4f a = *reinterpret_cast<const v4f*>(&tile[j][4 * h]);
      const v4f b = *reinterpret_cast<const v4f*>(&tile[j][64 + 4 * h]);
      v4f uA = xA - a,  uB = xB - b;         // v_pk_add (neg)
      v4f dA = uA * uA, dB = uB * uB;        // v_pk_mul
      v4f pv = dA + dB;                      // v_pk_add
      float pd = (pv.x + pv.y) + (pv.z + pv.w);
      SA += (v4f){fexp2(-dA.x), fexp2(-dA.y), fexp2(-dA.z), fexp2(-dA.w)};
      SB += (v4f){fexp2(-dB.x), fexp2(-dB.y), fexp2(-dB.z), fexp2(-dB.w)};
      // joint: rotate-butterfly sum over the 16 lanes of this row-group (VALU-only)
      pd += dpp_ror<0x121>(pd);   // ror 1
      pd += dpp_ror<0x122>(pd);   // ror 2
      pd += dpp_ror<0x124>(pd);   // ror 4
      pd += dpp_ror<0x128>(pd);   // ror 8
      jacc += fexp2(-pd);
    }
  }

  float* mrow = marg + (size_t)row * KDIM;
  atomicAdd(&mrow[4 * h + 0], SA.x);
  atomicAdd(&mrow[4 * h + 1], SA.y);
  atomicAdd(&mrow[4 * h + 2], SA.z);
  atomicAdd(&mrow[4 * h + 3], SA.w);
  atomicAdd(&mrow[64 + 4 * h + 0], SB.x);
  atomicAdd(&mrow[64 + 4 * h + 1], SB.y);
  atomicAdd(&mrow[64 + 4 * h + 2], SB.z);
  atomicAdd(&mrow[64 + 4 * h + 3], SB.w);
  if (h == 0) atomicAdd(&joint[row], jacc);
}

// ---------------- Kernel C: finalize ----------------------------------------
// v_i = ln2*(log2 Sj - sum_k log2 Sk) + 127*ln(2048); out = mean_i v_i
__global__ __launch_bounds__(256) void tc_final(const float* __restrict__ marg,
                                                const float* __restrict__ joint,
                                                float* __restrict__ out){
  const int r = blockIdx.x * 256 + threadIdx.x;
  const float* m = marg + (size_t)r * KDIM;
  float s = 0.f;
  #pragma unroll 4
  for (int k4 = 0; k4 < KDIM / 4; ++k4){
    float4 v = reinterpret_cast<const float4*>(m)[k4];
    s += flog2(v.x) + flog2(v.y) + flog2(v.z) + flog2(v.w);
  }
  // 127 * ln(2048) = 127 * 11 * ln 2
  float vi = 0.6931471805599453f * (flog2(joint[r]) - s) + 968.32661124224364f;
  for (int off = 32; off > 0; off >>= 1) vi += __shfl_down(vi, off);
  __shared__ float rs[4];
  const int wave = threadIdx.x >> 6, lane = threadIdx.x & 63;
  if (lane == 0) rs[wave] = vi;
  __syncthreads();
  if (threadIdx.x == 0){
    float tot = rs[0] + rs[1] + rs[2] + rs[3];
    atomicAdd(out, tot * (1.0f / NROWS));
  }
}

// ---------------- launch -----------------------------------------------------
extern "C" void kernel_launch(void* const* d_in, const int* in_sizes, int n_in,
                              void* d_out, int out_size, void* d_ws, size_t ws_size,
                              hipStream_t stream){
  const float* x = (const float*)d_in[0];
  float* out   = (float*)d_out;
  float* wsf   = (float*)d_ws;
  float* accum = wsf;                         // 256 floats (raw col sums)
  float* joint = wsf + 2 * KDIM;              // 2048 floats
  float* marg  = wsf + 2 * KDIM + NROWS;      // 2048*128 floats
  // one contiguous zero-fill of accum+joint+marg (ws is re-poisoned each launch)
  (void)hipMemsetAsync(wsf, 0, (size_t)(2 * KDIM + NROWS + NROWS * KDIM) * sizeof(float), stream);
  (void)hipMemsetAsync(d_out, 0, sizeof(float), stream);

  tc_stats<<<32, 1024, 0, stream>>>(x, accum);
  tc_main<<<dim3(64, 8), 512, 0, stream>>>(x, accum, marg, joint);
  tc_final<<<NROWS / 256, 256, 0, stream>>>(marg, joint, out);
}

// Round 5
// 131.911 us; speedup vs baseline: 1.3404x; 1.2398x over previous
//
#include <hip/hip_runtime.h>

#define NROWS 2048
#define KDIM  128
#define TJ    64
#define NCELL 16
#define PORD  10

typedef float v4f __attribute__((ext_vector_type(4)));

__device__ __forceinline__ float fexp2(float x){ return __builtin_amdgcn_exp2f(x); }
__device__ __forceinline__ float flog2(float x){ return __builtin_amdgcn_logf(x); }

// sqrt(1/(2*ln2)): exp2(-((t*CS)^2)) = exp(-t^2/2)
#define CS 0.8493218002880191f

template<int CTRL>
__device__ __forceinline__ float dpp_ror(float v){
  int r = __builtin_amdgcn_update_dpp(0, __builtin_bit_cast(int, v), CTRL, 0xF, 0xF, true);
  return __builtin_bit_cast(float, r);
}

// plain (un-folded) per-column standardization params from raw sums
__device__ __forceinline__ void col_stats(const float* __restrict__ accum, int k,
                                          float& scale, float& shift){
  float s = accum[k], s2 = accum[KDIM + k];
  float m = s * (1.f / NROWS);
  float var = fmaxf((s2 - (float)NROWS * m * m) * (1.f / (NROWS - 1)), 0.f);
  scale = 1.f / (sqrtf(var) + 1e-6f);
  shift = -m * scale;
}

// CS-folded quad stats (for the joint kernel's exp2 path)
__device__ __forceinline__ void quad_stats(const float* __restrict__ accum, int q,
                                           float4& sc, float4& sh){
  const float4 s  = reinterpret_cast<const float4*>(accum)[q];
  const float4 s2 = reinterpret_cast<const float4*>(accum + KDIM)[q];
  const float invN = 1.f / NROWS, invN1 = 1.f / (NROWS - 1);
#define COMP(c) { float m = s.c * invN; \
                  float var = fmaxf((s2.c - (float)NROWS * m * m) * invN1, 0.f); \
                  float sca = CS / (sqrtf(var) + 1e-6f); sc.c = sca; sh.c = -m * sca; }
  COMP(x) COMP(y) COMP(z) COMP(w)
#undef COMP
}

// ---------------- Kernel A: raw column sums (coalesced) ----------------------
__global__ __launch_bounds__(1024) void tc_stats(const float* __restrict__ x,
                                                 float* __restrict__ accum){
  const int t  = threadIdx.x;
  const int k  = t & 127;
  const int rg = t >> 7;               // 0..7
  const int r0 = blockIdx.x * 64;
  float s = 0.f, s2 = 0.f;
  #pragma unroll
  for (int it = 0; it < 8; ++it){
    float v = x[(size_t)(r0 + it * 8 + rg) * KDIM + k];
    s += v;
    s2 = fmaf(v, v, s2);
  }
  __shared__ float ls[8][128], ls2[8][128];
  ls[rg][k] = s; ls2[rg][k] = s2;
  __syncthreads();
  if (t < 128){
    float a = 0.f, b = 0.f;
    #pragma unroll
    for (int g = 0; g < 8; ++g){ a += ls[g][t]; b += ls2[g][t]; }
    atomicAdd(&accum[t], a);
    atomicAdd(&accum[128 + t], b);
  }
}

// ---------------- Kernel M1: FGT moments per column --------------------------
// grid 2048 = 128 k x 16 row-segs; 128 threads, 1 value each.
// mom2 layout: [(c*128 + k)*12 + m], m<10 used; moments pre-divided by m!.
__global__ __launch_bounds__(128) void tc_moments(const float* __restrict__ x,
                                                  const float* __restrict__ accum,
                                                  float* __restrict__ mom2){
  const int k   = blockIdx.x >> 4;
  const int seg = blockIdx.x & 15;
  const int t   = threadIdx.x;
  __shared__ float lm[NCELL * PORD];   // 160
  lm[t] = 0.f;
  if (t < 32) lm[128 + t] = 0.f;
  __syncthreads();

  float scale, shift; col_stats(accum, k, scale, shift);
  const int row = seg * 128 + t;
  float y = fmaf(x[(size_t)row * KDIM + k], scale, shift);
  int c = (int)floorf(y * 2.f + 8.f);          // (y+4)/0.5
  c = min(max(c, 0), NCELL - 1);
  float u = y - (-3.75f + 0.5f * (float)c);
  float* b10 = &lm[c * PORD];
  atomicAdd(&b10[0], 1.f);
  float pw = u;
  atomicAdd(&b10[1], pw);
  pw *= u; atomicAdd(&b10[2], pw * 0.5f);
  pw *= u; atomicAdd(&b10[3], pw * 1.6666666666e-1f);
  pw *= u; atomicAdd(&b10[4], pw * 4.1666666666e-2f);
  pw *= u; atomicAdd(&b10[5], pw * 8.3333333333e-3f);
  pw *= u; atomicAdd(&b10[6], pw * 1.3888888889e-3f);
  pw *= u; atomicAdd(&b10[7], pw * 1.9841269841e-4f);
  pw *= u; atomicAdd(&b10[8], pw * 2.4801587302e-5f);
  pw *= u; atomicAdd(&b10[9], pw * 2.7557319224e-6f);
  __syncthreads();

  for (int idx = t; idx < NCELL * PORD; idx += 128){
    int c2 = idx / PORD, m = idx - c2 * PORD;
    atomicAdd(&mom2[(size_t)(c2 * KDIM + k) * 12 + m], lm[idx]);
  }
}

// ---------------- Kernel M2: FGT evaluation + per-row log2 sum ---------------
// grid 1024 x 256: block = 2 rows x 128 k. slog[row] += sum_k log2(S_marg(row,k))
__global__ __launch_bounds__(256) void tc_eval(const float* __restrict__ x,
                                               const float* __restrict__ accum,
                                               const float* __restrict__ mom2,
                                               float* __restrict__ slog){
  const int t   = threadIdx.x;
  const int k   = t & 127;
  const int ir  = t >> 7;
  const int row = blockIdx.x * 2 + ir;
  float scale, shift; col_stats(accum, k, scale, shift);
  const float y = fmaf(x[(size_t)row * KDIM + k], scale, shift);

  float S = 0.f;
  #pragma unroll
  for (int c = 0; c < NCELL; ++c){
    const float* mp = mom2 + (size_t)(c * KDIM + k) * 12;
    float4 q0 = *reinterpret_cast<const float4*>(mp);
    float4 q1 = *reinterpret_cast<const float4*>(mp + 4);
    float4 q2 = *reinterpret_cast<const float4*>(mp + 8);
    float s  = y - (-3.75f + 0.5f * (float)c);
    float sc = s * CS;
    float e  = fexp2(-(sc * sc));
    // inner = sum_m M~_m * He_m(s), He_{m+1} = s*He_m - m*He_{m-1}
    float prev = 1.f, cur = s, nxt;
    float inner = fmaf(q0.y, s, q0.x);
    nxt = fmaf(s, cur, -prev);        inner = fmaf(q0.z, nxt, inner); prev = cur; cur = nxt;
    nxt = fmaf(s, cur, -2.f * prev);  inner = fmaf(q0.w, nxt, inner); prev = cur; cur = nxt;
    nxt = fmaf(s, cur, -3.f * prev);  inner = fmaf(q1.x, nxt, inner); prev = cur; cur = nxt;
    nxt = fmaf(s, cur, -4.f * prev);  inner = fmaf(q1.y, nxt, inner); prev = cur; cur = nxt;
    nxt = fmaf(s, cur, -5.f * prev);  inner = fmaf(q1.z, nxt, inner); prev = cur; cur = nxt;
    nxt = fmaf(s, cur, -6.f * prev);  inner = fmaf(q1.w, nxt, inner); prev = cur; cur = nxt;
    nxt = fmaf(s, cur, -7.f * prev);  inner = fmaf(q2.x, nxt, inner); prev = cur; cur = nxt;
    nxt = fmaf(s, cur, -8.f * prev);  inner = fmaf(q2.y, nxt, inner);
    S = fmaf(e, inner, S);
  }
  float lg = flog2(S);
  #pragma unroll
  for (int off = 1; off < 64; off <<= 1) lg += __shfl_xor(lg, off);
  if ((t & 63) == 0) atomicAdd(&slog[row], lg);
}

// ---------------- Kernel J: joint pairwise distances -------------------------
// Wave: 4 rows (g=lane>>4), 16 lanes/row, 8 k's/lane. Block 512 = 32 rows.
// Grid (64 i-tiles, 8 j-chunks of 256). exp skipped unless some lane is near.
__global__ __launch_bounds__(512) void tc_joint(const float* __restrict__ x,
                                                const float* __restrict__ accum,
                                                float* __restrict__ joint){
  __shared__ float tile[TJ][KDIM];     // 32 KB
  const int t    = threadIdx.x;
  const int wave = t >> 6;
  const int lane = t & 63;
  const int g    = lane >> 4;
  const int h    = lane & 15;
  const int row  = blockIdx.x * 32 + wave * 4 + g;
  const int jbase = blockIdx.y * 256;

  const int kq = t & 31;
  float4 sc4, sh4; quad_stats(accum, kq, sc4, sh4);

  v4f xA, xB;
  {
    float4 scA, shA, scB, shB;
    quad_stats(accum, h,      scA, shA);
    quad_stats(accum, 16 + h, scB, shB);
    float4 rA = reinterpret_cast<const float4*>(x + (size_t)row * KDIM)[h];
    float4 rB = reinterpret_cast<const float4*>(x + (size_t)row * KDIM)[16 + h];
    xA = (v4f){fmaf(rA.x, scA.x, shA.x), fmaf(rA.y, scA.y, shA.y),
               fmaf(rA.z, scA.z, shA.z), fmaf(rA.w, scA.w, shA.w)};
    xB = (v4f){fmaf(rB.x, scB.x, shB.x), fmaf(rB.y, scB.y, shB.y),
               fmaf(rB.z, scB.z, shB.z), fmaf(rB.w, scB.w, shB.w)};
  }

  float jacc = 0.f;
  const int jr0 = t >> 5;

  for (int jt = 0; jt < 256; jt += TJ){
    __syncthreads();
    #pragma unroll
    for (int p = 0; p < 4; ++p){
      const int jr = jr0 + 16 * p;
      float4 v = reinterpret_cast<const float4*>(x + (size_t)(jbase + jt + jr) * KDIM)[kq];
      v4f w = {fmaf(v.x, sc4.x, sh4.x), fmaf(v.y, sc4.y, sh4.y),
               fmaf(v.z, sc4.z, sh4.z), fmaf(v.w, sc4.w, sh4.w)};
      *reinterpret_cast<v4f*>(&tile[jr][kq * 4]) = w;
    }
    __syncthreads();

    #pragma unroll 8
    for (int j = 0; j < TJ; ++j){
      const v4f a = *reinterpret_cast<const v4f*>(&tile[j][4 * h]);
      const v4f b = *reinterpret_cast<const v4f*>(&tile[j][64 + 4 * h]);
      v4f uA = xA - a, uB = xB - b;
      float pd = uA.x * uA.x;
      pd = fmaf(uA.y, uA.y, pd); pd = fmaf(uA.z, uA.z, pd); pd = fmaf(uA.w, uA.w, pd);
      pd = fmaf(uB.x, uB.x, pd); pd = fmaf(uB.y, uB.y, pd);
      pd = fmaf(uB.z, uB.z, pd); pd = fmaf(uB.w, uB.w, pd);
      pd += dpp_ror<0x121>(pd);
      pd += dpp_ror<0x122>(pd);
      pd += dpp_ror<0x124>(pd);
      pd += dpp_ror<0x128>(pd);
      // pd is now the full CS-folded 128-dim sqdist for (row, jbase+jt+j).
      if (__ballot(pd < 65.f)) jacc += fexp2(-pd);   // wave-uniform skip
    }
  }
  if (h == 0) atomicAdd(&joint[row], jacc);
}

// ---------------- Kernel C: finalize ----------------------------------------
__global__ __launch_bounds__(256) void tc_final(const float* __restrict__ joint,
                                                const float* __restrict__ slog,
                                                float* __restrict__ out){
  const int r = blockIdx.x * 256 + threadIdx.x;
  // v_i = ln2*(log2 Sj - sum_k log2 Sk) + 127*ln(2048)
  float vi = 0.6931471805599453f * (flog2(joint[r]) - slog[r]) + 968.32661124224364f;
  #pragma unroll
  for (int off = 32; off > 0; off >>= 1) vi += __shfl_down(vi, off);
  __shared__ float rs[4];
  const int wave = threadIdx.x >> 6, lane = threadIdx.x & 63;
  if (lane == 0) rs[wave] = vi;
  __syncthreads();
  if (threadIdx.x == 0){
    float tot = rs[0] + rs[1] + rs[2] + rs[3];
    atomicAdd(out, tot * (1.0f / NROWS));
  }
}

// ---------------- launch -----------------------------------------------------
extern "C" void kernel_launch(void* const* d_in, const int* in_sizes, int n_in,
                              void* d_out, int out_size, void* d_ws, size_t ws_size,
                              hipStream_t stream){
  const float* x = (const float*)d_in[0];
  float* out   = (float*)d_out;
  float* wsf   = (float*)d_ws;
  float* accum = wsf;                  // 256
  float* joint = wsf + 256;            // 2048
  float* slog  = wsf + 256 + 2048;     // 2048
  float* mom2  = wsf + 256 + 4096;     // 16*128*12 = 24576
  const size_t ws_floats = 256 + 4096 + 24576;
  (void)hipMemsetAsync(wsf, 0, ws_floats * sizeof(float), stream);
  (void)hipMemsetAsync(d_out, 0, sizeof(float), stream);

  tc_stats  <<<32, 1024, 0, stream>>>(x, accum);
  tc_moments<<<KDIM * 16, 128, 0, stream>>>(x, accum, mom2);
  tc_joint  <<<dim3(64, 8), 512, 0, stream>>>(x, accum, joint);
  tc_eval   <<<NROWS / 2, 256, 0, stream>>>(x, accum, mom2, slog);
  tc_final  <<<NROWS / 256, 256, 0, stream>>>(joint, slog, out);
}

// Round 6
// 116.402 us; speedup vs baseline: 1.5190x; 1.1332x over previous
//
#include <hip/hip_runtime.h>

#define NROWS 2048
#define KDIM  128
#define TJ    64
#define NCELL 16
#define PORD  10
#define NJBLK 576   // 36 pairs x 8 i-subtiles x 2 j-halves

typedef float v4f __attribute__((ext_vector_type(4)));

__device__ __forceinline__ float fexp2(float x){ return __builtin_amdgcn_exp2f(x); }
__device__ __forceinline__ float flog2(float x){ return __builtin_amdgcn_logf(x); }

// sqrt(1/(2*ln2)): exp2(-((t*CS)^2)) = exp(-t^2/2)
#define CS 0.8493218002880191f

template<int CTRL>
__device__ __forceinline__ float dpp_ror(float v){
  int r = __builtin_amdgcn_update_dpp(0, __builtin_bit_cast(int, v), CTRL, 0xF, 0xF, true);
  return __builtin_bit_cast(float, r);
}

// ws float layout
#define OFF_PART   0            // 32*256 partial col sums
#define OFF_ACCUM  8192         // 256 final col sums (written by moments k-blocks seg==0)
#define OFF_JOINT  8448         // 2048
#define OFF_SLOG   10496        // 2048
#define OFF_MOM    12544        // 16*128*10 = 20480
#define OFF_CTR    33024        // 4 (uint counter)
#define ZERO_BASE  OFF_JOINT
#define ZERO_LEN   (2048 + 2048 + 20480 + 4)

__device__ __forceinline__ void col_stats_from(float s, float s2, float& scale, float& shift){
  float m = s * (1.f / NROWS);
  float var = fmaxf((s2 - (float)NROWS * m * m) * (1.f / (NROWS - 1)), 0.f);
  scale = 1.f / (sqrtf(var) + 1e-6f);
  shift = -m * scale;
}

__device__ __forceinline__ void quad_stats(const float* __restrict__ accum, int q,
                                           float4& sc, float4& sh){
  const float4 s  = reinterpret_cast<const float4*>(accum)[q];
  const float4 s2 = reinterpret_cast<const float4*>(accum + KDIM)[q];
  const float invN = 1.f / NROWS, invN1 = 1.f / (NROWS - 1);
#define COMP(c) { float m = s.c * invN; \
                  float var = fmaxf((s2.c - (float)NROWS * m * m) * invN1, 0.f); \
                  float sca = CS / (sqrtf(var) + 1e-6f); sc.c = sca; sh.c = -m * sca; }
  COMP(x) COMP(y) COMP(z) COMP(w)
#undef COMP
}

// ---------------- D1: partial col sums + zero accumulators -------------------
__global__ __launch_bounds__(1024) void tc_stats(const float* __restrict__ x,
                                                 float* __restrict__ ws){
  const int t  = threadIdx.x;
  const int k  = t & 127;
  const int rg = t >> 7;
  const int r0 = blockIdx.x * 64;
  // zero the accumulator region (32768 threads cover ZERO_LEN=24580)
  {
    int idx = blockIdx.x * 1024 + t;
    if (idx < ZERO_LEN) ws[ZERO_BASE + idx] = 0.f;
  }
  float s = 0.f, s2 = 0.f;
  #pragma unroll
  for (int it = 0; it < 8; ++it){
    float v = x[(size_t)(r0 + it * 8 + rg) * KDIM + k];
    s += v;
    s2 = fmaf(v, v, s2);
  }
  __shared__ float ls[8][128], ls2[8][128];
  ls[rg][k] = s; ls2[rg][k] = s2;
  __syncthreads();
  if (t < 128){
    float a = 0.f, b = 0.f;
    #pragma unroll
    for (int g = 0; g < 8; ++g){ a += ls[g][t]; b += ls2[g][t]; }
    ws[OFF_PART + blockIdx.x * 256 + t]       = a;
    ws[OFF_PART + blockIdx.x * 256 + 128 + t] = b;
  }
}

// ---------------- D2: FGT moments (+ write final accum) ----------------------
// grid 2048 = 128 k x 16 row-segs; 128 threads.
__global__ __launch_bounds__(128) void tc_moments(const float* __restrict__ x,
                                                  float* __restrict__ ws){
  const int k   = blockIdx.x >> 4;
  const int seg = blockIdx.x & 15;
  const int t   = threadIdx.x;
  __shared__ float lm[NCELL * PORD];   // 160
  lm[t] = 0.f;
  if (t < 32) lm[128 + t] = 0.f;

  float s = 0.f, s2 = 0.f;
  #pragma unroll
  for (int b = 0; b < 32; ++b){
    s  += ws[OFF_PART + b * 256 + k];
    s2 += ws[OFF_PART + b * 256 + 128 + k];
  }
  if (seg == 0 && t == 0){
    ws[OFF_ACCUM + k]       = s;
    ws[OFF_ACCUM + 128 + k] = s2;
  }
  float scale, shift; col_stats_from(s, s2, scale, shift);
  __syncthreads();

  const int row = seg * 128 + t;
  float y = fmaf(x[(size_t)row * KDIM + k], scale, shift);
  int c = (int)floorf(y * 2.f + 8.f);
  c = min(max(c, 0), NCELL - 1);
  float u = y - (-3.75f + 0.5f * (float)c);
  float* b10 = &lm[c * PORD];
  atomicAdd(&b10[0], 1.f);
  float pw = u;
  atomicAdd(&b10[1], pw);
  pw *= u; atomicAdd(&b10[2], pw * 0.5f);
  pw *= u; atomicAdd(&b10[3], pw * 1.6666666666e-1f);
  pw *= u; atomicAdd(&b10[4], pw * 4.1666666666e-2f);
  pw *= u; atomicAdd(&b10[5], pw * 8.3333333333e-3f);
  pw *= u; atomicAdd(&b10[6], pw * 1.3888888889e-3f);
  pw *= u; atomicAdd(&b10[7], pw * 1.9841269841e-4f);
  pw *= u; atomicAdd(&b10[8], pw * 2.4801587302e-5f);
  pw *= u; atomicAdd(&b10[9], pw * 2.7557319224e-6f);
  __syncthreads();

  float* mom = ws + OFF_MOM;
  for (int idx = t; idx < NCELL * PORD; idx += 128){
    int c2 = idx / PORD, m = idx - c2 * PORD;
    atomicAdd(&mom[(size_t)(c2 * KDIM + k) * PORD + m], lm[idx]);
  }
}

// ---------------- D3: symmetric joint + FGT eval + final ---------------------
// bid = pair*16 + sub*2 + jhalf. pair->(a,b) upper triangle of 8 chunks of 256.
__global__ __launch_bounds__(512) void tc_joint(const float* __restrict__ x,
                                                float* __restrict__ ws,
                                                float* __restrict__ out){
  __shared__ float tile[TJ][KDIM];     // 32 KB
  __shared__ float colacc[128];
  __shared__ int   lastflag;
  const float* accum = ws + OFF_ACCUM;
  float* joint = ws + OFF_JOINT;
  float* slog  = ws + OFF_SLOG;
  const float* mom = ws + OFF_MOM;

  const int bid  = blockIdx.x;
  const int t    = threadIdx.x;
  const int wave = t >> 6;
  const int lane = t & 63;
  const int g    = lane >> 4;
  const int h    = lane & 15;

  int pair = bid >> 4, sub = (bid >> 1) & 7, jhalf = bid & 1;
  int a = 0, rem = pair;
  while (rem >= 8 - a){ rem -= 8 - a; ++a; }
  const int b = a + rem;
  const int i0 = a * 256 + sub * 32;
  const int j0 = b * 256 + jhalf * 128;
  const bool offdiag = (a != b);

  const int row = i0 + wave * 4 + g;

  if (t < 128) colacc[t] = 0.f;

  const int kq = t & 31;
  float4 sc4, sh4; quad_stats(accum, kq, sc4, sh4);

  v4f xA, xB;
  {
    float4 scA, shA, scB, shB;
    quad_stats(accum, h,      scA, shA);
    quad_stats(accum, 16 + h, scB, shB);
    float4 rA = reinterpret_cast<const float4*>(x + (size_t)row * KDIM)[h];
    float4 rB = reinterpret_cast<const float4*>(x + (size_t)row * KDIM)[16 + h];
    xA = (v4f){fmaf(rA.x, scA.x, shA.x), fmaf(rA.y, scA.y, shA.y),
               fmaf(rA.z, scA.z, shA.z), fmaf(rA.w, scA.w, shA.w)};
    xB = (v4f){fmaf(rB.x, scB.x, shB.x), fmaf(rB.y, scB.y, shB.y),
               fmaf(rB.z, scB.z, shB.z), fmaf(rB.w, scB.w, shB.w)};
  }

  float jacc = 0.f;
  const int jr0 = t >> 5;

  for (int jt = 0; jt < 128; jt += TJ){
    __syncthreads();
    #pragma unroll
    for (int p = 0; p < 4; ++p){
      const int jr = jr0 + 16 * p;
      float4 v = reinterpret_cast<const float4*>(x + (size_t)(j0 + jt + jr) * KDIM)[kq];
      v4f w = {fmaf(v.x, sc4.x, sh4.x), fmaf(v.y, sc4.y, sh4.y),
               fmaf(v.z, sc4.z, sh4.z), fmaf(v.w, sc4.w, sh4.w)};
      *reinterpret_cast<v4f*>(&tile[jr][kq * 4]) = w;
    }
    __syncthreads();

    #pragma unroll 8
    for (int j = 0; j < TJ; ++j){
      const v4f aa = *reinterpret_cast<const v4f*>(&tile[j][4 * h]);
      const v4f bb = *reinterpret_cast<const v4f*>(&tile[j][64 + 4 * h]);
      v4f uA = xA - aa, uB = xB - bb;
      float p0 = uA.x * uA.x, p1 = uA.y * uA.y;
      p0 = fmaf(uA.z, uA.z, p0); p1 = fmaf(uA.w, uA.w, p1);
      p0 = fmaf(uB.x, uB.x, p0); p1 = fmaf(uB.y, uB.y, p1);
      p0 = fmaf(uB.z, uB.z, p0); p1 = fmaf(uB.w, uB.w, p1);
      float pd = p0 + p1;
      pd += dpp_ror<0x121>(pd);
      pd += dpp_ror<0x122>(pd);
      pd += dpp_ror<0x124>(pd);
      pd += dpp_ror<0x128>(pd);
      if (__ballot(pd < 65.f)){
        float e = fexp2(-pd);
        jacc += e;
        if (offdiag && h == 0) atomicAdd(&colacc[jt + j], e);
      }
    }
  }

  if (h == 0) atomicAdd(&joint[row], jacc);
  __syncthreads();
  if (offdiag && t < 128){
    float c = colacc[t];
    if (c != 0.f) atomicAdd(&joint[j0 + t], c);
  }

  // ---- FGT eval: first 512 blocks handle 4 rows x 128 k each ----
  if (bid < 512){
    const int k  = t & 127;
    const int ir = t >> 7;
    const int r  = bid * 4 + ir;
    float scale, shift;
    col_stats_from(accum[k], accum[128 + k], scale, shift);
    const float y = fmaf(x[(size_t)r * KDIM + k], scale, shift);
    float S = 0.f;
    #pragma unroll
    for (int c = 0; c < NCELL; ++c){
      const float* mp = mom + (size_t)(c * KDIM + k) * PORD;
      float q0 = mp[0], q1 = mp[1], q2 = mp[2], q3 = mp[3], q4 = mp[4];
      float q5 = mp[5], q6 = mp[6], q7 = mp[7], q8 = mp[8], q9 = mp[9];
      float s  = y - (-3.75f + 0.5f * (float)c);
      float scl = s * CS;
      float e  = fexp2(-(scl * scl));
      float prev = 1.f, cur = s, nxt;
      float inner = fmaf(q1, s, q0);
      nxt = fmaf(s, cur, -prev);        inner = fmaf(q2, nxt, inner); prev = cur; cur = nxt;
      nxt = fmaf(s, cur, -2.f * prev);  inner = fmaf(q3, nxt, inner); prev = cur; cur = nxt;
      nxt = fmaf(s, cur, -3.f * prev);  inner = fmaf(q4, nxt, inner); prev = cur; cur = nxt;
      nxt = fmaf(s, cur, -4.f * prev);  inner = fmaf(q5, nxt, inner); prev = cur; cur = nxt;
      nxt = fmaf(s, cur, -5.f * prev);  inner = fmaf(q6, nxt, inner); prev = cur; cur = nxt;
      nxt = fmaf(s, cur, -6.f * prev);  inner = fmaf(q7, nxt, inner); prev = cur; cur = nxt;
      nxt = fmaf(s, cur, -7.f * prev);  inner = fmaf(q8, nxt, inner); prev = cur; cur = nxt;
      nxt = fmaf(s, cur, -8.f * prev);  inner = fmaf(q9, nxt, inner);
      S = fmaf(e, inner, S);
    }
    float lg = flog2(S);
    #pragma unroll
    for (int off = 1; off < 64; off <<= 1) lg += __shfl_xor(lg, off);
    if (lane == 0) atomicAdd(&slog[r], lg);
  }

  // ---- arrival counter; last block finalizes ----
  __syncthreads();
  if (t == 0){
    __threadfence();
    unsigned int* ctr = (unsigned int*)(ws + OFF_CTR);
    unsigned int old = __hip_atomic_fetch_add(ctr, 1u, __ATOMIC_ACQ_REL, __HIP_MEMORY_SCOPE_AGENT);
    lastflag = (old == NJBLK - 1);
  }
  __syncthreads();
  if (lastflag){
    __shared__ float red[8];
    float acc = 0.f;
    #pragma unroll
    for (int q = 0; q < 4; ++q){
      int r = q * 512 + t;
      float jv = __hip_atomic_load(&joint[r], __ATOMIC_RELAXED, __HIP_MEMORY_SCOPE_AGENT);
      float sv = __hip_atomic_load(&slog[r],  __ATOMIC_RELAXED, __HIP_MEMORY_SCOPE_AGENT);
      acc += 0.6931471805599453f * (flog2(jv) - sv);
    }
    #pragma unroll
    for (int off = 1; off < 64; off <<= 1) acc += __shfl_xor(acc, off);
    if (lane == 0) red[wave] = acc;
    __syncthreads();
    if (t == 0){
      float tot = 0.f;
      #pragma unroll
      for (int w2 = 0; w2 < 8; ++w2) tot += red[w2];
      // + 127*ln(2048) per row, averaged -> constant
      out[0] = tot * (1.0f / NROWS) + 968.32661124224364f;
    }
  }
}

// ---------------- launch -----------------------------------------------------
extern "C" void kernel_launch(void* const* d_in, const int* in_sizes, int n_in,
                              void* d_out, int out_size, void* d_ws, size_t ws_size,
                              hipStream_t stream){
  const float* x = (const float*)d_in[0];
  float* out = (float*)d_out;
  float* ws  = (float*)d_ws;

  tc_stats  <<<32, 1024, 0, stream>>>(x, ws);
  tc_moments<<<KDIM * 16, 128, 0, stream>>>(x, ws);
  tc_joint  <<<NJBLK, 512, 0, stream>>>(x, ws, out);
}